// Round 1
// baseline (501.696 us; speedup 1.0000x reference)
//
#include <hip/hip_runtime.h>
#include <hip/hip_bf16.h>

// MultiHeadAttentionPool3D: B=4, C=256, S=32*32*32=32768, F=512, NH=8, HD=64, Q=4
// Key algebra: keys/values [B,F,S] are never materialized.
//   scores[b,hq,s] = qW[hq,:]·x[b,:,s] + qb[hq]      (qW = 0.125 * q^T Wk, [32][256])
//   attended[b,hq,:] = Wv·ax[b,hq,:] + bv            (ax = sum_s attn*x, since sum attn = 1)

#define NHh 8
#define Qq 4
#define Ff 512
#define Cc 256
#define HDd 64
#define HQ 32
#define Ss 32768
#define NCH2 16
#define CH2 2048
#define NCH3 64
#define CH3 512
#define LN_EPSf 1e-5f

// ---------------- K0: fold queries into Wk ----------------
__global__ void k0_prep(const float* __restrict__ q, const float* __restrict__ Wk,
                        const float* __restrict__ bk, float* __restrict__ qWT,
                        float* __restrict__ qb) {
    int hq = blockIdx.x;          // 32 blocks
    int h = hq >> 2, qq = hq & 3;
    int c = threadIdx.x;          // 256 threads
    float acc = 0.f;
    for (int d = 0; d < HDd; ++d)
        acc += q[qq * Ff + h * HDd + d] * Wk[(h * HDd + d) * Cc + c];
    qWT[c * HQ + hq] = acc * 0.125f;   // transposed [c][hq], scale folded
    if (c == 0) {
        float a = 0.f;
        for (int d = 0; d < HDd; ++d) a += q[qq * Ff + h * HDd + d] * bk[h * HDd + d];
        qb[hq] = a * 0.125f;
    }
}

// ---------------- K1: scoresT[b][s][hq] = qW·x + qb ----------------
__global__ __launch_bounds__(256) void k1_scores(const float* __restrict__ x,
                                                 const float* __restrict__ qWT,
                                                 const float* __restrict__ qb,
                                                 float* __restrict__ scoresT) {
    int b = blockIdx.y;
    int s = blockIdx.x * 256 + threadIdx.x;   // lanes along s -> x loads coalesced
    const float* xb = x + (size_t)b * Cc * Ss + s;
    float acc[HQ];
#pragma unroll
    for (int r = 0; r < HQ; ++r) acc[r] = qb[r];
    const float4* qw4 = (const float4*)qWT;   // uniform-address loads (scalarizable)
    for (int c = 0; c < Cc; ++c) {
        float xv = xb[(size_t)c * Ss];
#pragma unroll
        for (int u = 0; u < 8; ++u) {
            float4 w = qw4[c * 8 + u];
            acc[u * 4 + 0] += w.x * xv;
            acc[u * 4 + 1] += w.y * xv;
            acc[u * 4 + 2] += w.z * xv;
            acc[u * 4 + 3] += w.w * xv;
        }
    }
    float4* out4 = (float4*)(scoresT + ((size_t)b * Ss + s) * HQ);
#pragma unroll
    for (int u = 0; u < 8; ++u)
        out4[u] = make_float4(acc[u * 4], acc[u * 4 + 1], acc[u * 4 + 2], acc[u * 4 + 3]);
}

// ---------------- K2a: per-(row, chunk) partial max / expsum ----------------
__global__ __launch_bounds__(256) void k2a_stats(const float* __restrict__ scoresT,
                                                 float* __restrict__ pml) {
    int b = blockIdx.y, ch = blockIdx.x;
    int t = threadIdx.x, hq = t & 31, so = t >> 5;
    const float* base = scoresT + ((size_t)b * Ss + ch * CH2) * HQ + hq;
    float m = -1e30f;
    for (int k = 0; k < CH2 / 8; ++k) m = fmaxf(m, base[(so + k * 8) * HQ]);
    float l = 0.f;
    for (int k = 0; k < CH2 / 8; ++k) l += __expf(base[(so + k * 8) * HQ] - m);
    // lanes hq and hq+32 combine
    float mo = __shfl_xor(m, 32);
    float lo = __shfl_xor(l, 32);
    float M = fmaxf(m, mo);
    l = l * __expf(m - M) + lo * __expf(mo - M);
    m = M;
    __shared__ float rm[4][32], rl[4][32];
    int w = t >> 6;
    if ((t & 63) < 32) { rm[w][hq] = m; rl[w][hq] = l; }
    __syncthreads();
    if (t < 32) {
        float M2 = rm[0][t];
        for (int ww = 1; ww < 4; ++ww) M2 = fmaxf(M2, rm[ww][t]);
        float L = 0.f;
        for (int ww = 0; ww < 4; ++ww) L += rl[ww][t] * __expf(rm[ww][t] - M2);
        int row = b * HQ + t;
        pml[(row * NCH2 + ch) * 2 + 0] = M2;
        pml[(row * NCH2 + ch) * 2 + 1] = L;
    }
}

// ---------------- K2b: combine chunk stats per row ----------------
__global__ void k2b_combine(const float* __restrict__ pml, float* __restrict__ Mrow,
                            float* __restrict__ iLrow) {
    int row = threadIdx.x;   // 128 threads, 1 block
    float M = -1e30f;
    for (int ch = 0; ch < NCH2; ++ch) M = fmaxf(M, pml[(row * NCH2 + ch) * 2]);
    float L = 0.f;
    for (int ch = 0; ch < NCH2; ++ch)
        L += pml[(row * NCH2 + ch) * 2 + 1] * __expf(pml[(row * NCH2 + ch) * 2] - M);
    Mrow[row] = M;
    iLrow[row] = 1.f / L;
}

// ---------------- K2c: normalize in place: p = exp(v-M)/L ----------------
__global__ __launch_bounds__(256) void k2c_norm(float* __restrict__ pT,
                                                const float* __restrict__ Mrow,
                                                const float* __restrict__ iLrow) {
    int b = blockIdx.y, ch = blockIdx.x;
    int t = threadIdx.x, hq = t & 31, so = t >> 5;
    float M = Mrow[b * HQ + hq], iL = iLrow[b * HQ + hq];
    float* base = pT + ((size_t)b * Ss + ch * CH2) * HQ + hq;
    for (int k = 0; k < CH2 / 8; ++k) {
        float v = base[(so + k * 8) * HQ];
        base[(so + k * 8) * HQ] = __expf(v - M) * iL;
    }
}

// ---------------- K3: partial ax[b][ch][hq][c] = sum_s p*x ----------------
__global__ __launch_bounds__(256) void k3_ax(const float* __restrict__ x,
                                             const float* __restrict__ pT,
                                             float* __restrict__ part) {
    int b = blockIdx.y, ch = blockIdx.x;
    int c = threadIdx.x;                 // thread owns channel c
    int s0 = ch * CH3;
    __shared__ float p_lds[64][HQ];      // 8 KB sub-tile, broadcast reads
    float acc[HQ];
#pragma unroll
    for (int r = 0; r < HQ; ++r) acc[r] = 0.f;
    const float* xb = x + ((size_t)b * Cc + c) * Ss;
    for (int sub = 0; sub < CH3 / 64; ++sub) {
        int sbase = s0 + sub * 64;
        __syncthreads();
        const float4* src = (const float4*)(pT + ((size_t)b * Ss + sbase) * HQ);
        float4* dst = (float4*)&p_lds[0][0];
        dst[threadIdx.x] = src[threadIdx.x];
        dst[threadIdx.x + 256] = src[threadIdx.x + 256];
        __syncthreads();
#pragma unroll 4
        for (int j = 0; j < 16; ++j) {
            float4 xv = *(const float4*)(xb + sbase + j * 4);
#pragma unroll
            for (int e = 0; e < 4; ++e) {
                float xs = (e == 0) ? xv.x : (e == 1) ? xv.y : (e == 2) ? xv.z : xv.w;
                const float4* pr = (const float4*)&p_lds[j * 4 + e][0];
#pragma unroll
                for (int u = 0; u < 8; ++u) {
                    float4 pv = pr[u];
                    acc[u * 4 + 0] += pv.x * xs;
                    acc[u * 4 + 1] += pv.y * xs;
                    acc[u * 4 + 2] += pv.z * xs;
                    acc[u * 4 + 3] += pv.w * xs;
                }
            }
        }
    }
    float* pb = part + (((size_t)b * NCH3 + ch) * HQ) * Cc + c;
#pragma unroll
    for (int r = 0; r < HQ; ++r) pb[r * Cc] = acc[r];
}

// ---------------- K3b: reduce partials -> ax[b][hq][c] ----------------
__global__ void k3b_red(const float* __restrict__ part, float* __restrict__ ax) {
    int hq = blockIdx.x, b = blockIdx.y, c = threadIdx.x;
    float s = 0.f;
    for (int ch = 0; ch < NCH3; ++ch)
        s += part[(((size_t)b * NCH3 + ch) * HQ + hq) * Cc + c];
    ax[((size_t)b * HQ + hq) * Cc + c] = s;
}

// ---------------- K4a: attended -> multi[b][q*512+h*64+d] ----------------
__global__ __launch_bounds__(256) void k4a_att(const float* __restrict__ ax,
                                               const float* __restrict__ Wv,
                                               const float* __restrict__ bv,
                                               float* __restrict__ multi) {
    int b = blockIdx.x, t = threadIdx.x;
    __shared__ float axl[HQ][Cc];
    for (int r = 0; r < HQ; ++r) axl[r][t] = ax[((size_t)b * HQ + r) * Cc + t];
    __syncthreads();
#pragma unroll
    for (int k = 0; k < 8; ++k) {
        int i = k * 256 + t;
        int qq = i >> 9, h = (i >> 6) & 7, d = i & 63;
        int hq = h * 4 + qq, row = h * 64 + d;
        float dot = bv[row];
        const float4* wr = (const float4*)(Wv + row * Cc);
        const float4* ar = (const float4*)&axl[hq][0];
        for (int c4 = 0; c4 < Cc / 4; ++c4) {
            float4 w = wr[c4], a = ar[c4];
            dot += w.x * a.x + w.y * a.y + w.z * a.z + w.w * a.w;
        }
        multi[b * 2048 + i] = dot;   // [B, Q*F] with index q*512 + h*64 + d
    }
}

// ---------------- K4b: out_pre[b][f] = multi[b]·Wo[f] + bo[f] ----------------
__global__ __launch_bounds__(256) void k4b_out(const float* __restrict__ multi,
                                               const float* __restrict__ Wo,
                                               const float* __restrict__ bo,
                                               float* __restrict__ out_pre) {
    int fc = blockIdx.x;   // 16 blocks * 32 f each
    int t = threadIdx.x;
    int fl = t >> 3, jo = t & 7;
    int f = fc * 32 + fl;
    __shared__ float ml[4][2048];
    for (int k = 0; k < 32; ++k) {
        int idx = k * 256 + t;
        ml[idx >> 11][idx & 2047] = multi[idx];
    }
    __syncthreads();
    float acc[4] = {0.f, 0.f, 0.f, 0.f};
    const float4* wr = (const float4*)(Wo + (size_t)f * 2048 + jo * 256);
    for (int jj = 0; jj < 64; ++jj) {
        float4 w = wr[jj];
#pragma unroll
        for (int bb = 0; bb < 4; ++bb) {
            const float4* m4 = (const float4*)&ml[bb][jo * 256];
            float4 m = m4[jj];
            acc[bb] += w.x * m.x + w.y * m.y + w.z * m.z + w.w * m.w;
        }
    }
#pragma unroll
    for (int o = 1; o < 8; o <<= 1) {
#pragma unroll
        for (int bb = 0; bb < 4; ++bb) acc[bb] += __shfl_xor(acc[bb], o);
    }
    if (jo == 0) {
#pragma unroll
        for (int bb = 0; bb < 4; ++bb) out_pre[bb * Ff + f] = acc[bb] + bo[f];
    }
}

// ---------------- K4c: LayerNorm over F=512 ----------------
__global__ __launch_bounds__(512) void k4c_ln(const float* __restrict__ out_pre,
                                              const float* __restrict__ gamma,
                                              const float* __restrict__ beta,
                                              float* __restrict__ out) {
    int b = blockIdx.x, t = threadIdx.x;
    float v = out_pre[b * Ff + t];
    float s = v;
#pragma unroll
    for (int o = 1; o < 64; o <<= 1) s += __shfl_xor(s, o);
    __shared__ float red[8], red2[8];
    int w = t >> 6;
    if ((t & 63) == 0) red[w] = s;
    __syncthreads();
    float mu = 0.f;
#pragma unroll
    for (int ww = 0; ww < 8; ++ww) mu += red[ww];
    mu *= (1.f / Ff);
    float d = v - mu;
    float s2 = d * d;
#pragma unroll
    for (int o = 1; o < 64; o <<= 1) s2 += __shfl_xor(s2, o);
    if ((t & 63) == 0) red2[w] = s2;
    __syncthreads();
    float var = 0.f;
#pragma unroll
    for (int ww = 0; ww < 8; ++ww) var += red2[ww];
    var *= (1.f / Ff);
    out[b * Ff + t] = d * rsqrtf(var + LN_EPSf) * gamma[t] + beta[t];
}

extern "C" void kernel_launch(void* const* d_in, const int* in_sizes, int n_in,
                              void* d_out, int out_size, void* d_ws, size_t ws_size,
                              hipStream_t stream) {
    const float* x       = (const float*)d_in[0];
    const float* queries = (const float*)d_in[1];
    const float* Wk      = (const float*)d_in[2];
    const float* bk      = (const float*)d_in[3];
    const float* Wv      = (const float*)d_in[4];
    const float* bv      = (const float*)d_in[5];
    const float* Wo      = (const float*)d_in[6];
    const float* bo      = (const float*)d_in[7];
    const float* gamma   = (const float*)d_in[8];
    const float* beta    = (const float*)d_in[9];
    float* out = (float*)d_out;
    float* ws  = (float*)d_ws;

    // ws layout (floats); total ~25.4 MB
    float* qWT     = ws;              // 8192
    float* qb      = ws + 8192;       // 32
    float* Mrow    = ws + 8320;       // 128
    float* iLrow   = ws + 8448;       // 128
    float* pml     = ws + 8576;       // 4096
    float* multi   = ws + 12672;      // 8192
    float* out_pre = ws + 20864;      // 2048
    float* ax      = ws + 22912;      // 32768
    float* scoresT = ws + 65536;      // 4,194,304  (doubles as pT in place)
    float* part    = ws + 65536 + 4194304;  // 2,097,152

    k0_prep   <<<32, 256, 0, stream>>>(queries, Wk, bk, qWT, qb);
    k1_scores <<<dim3(128, 4), 256, 0, stream>>>(x, qWT, qb, scoresT);
    k2a_stats <<<dim3(NCH2, 4), 256, 0, stream>>>(scoresT, pml);
    k2b_combine<<<1, 128, 0, stream>>>(pml, Mrow, iLrow);
    k2c_norm  <<<dim3(NCH2, 4), 256, 0, stream>>>(scoresT, Mrow, iLrow);
    k3_ax     <<<dim3(NCH3, 4), 256, 0, stream>>>(x, scoresT, part);
    k3b_red   <<<dim3(HQ, 4), 256, 0, stream>>>(part, ax);
    k4a_att   <<<4, 256, 0, stream>>>(ax, Wv, bv, multi);
    k4b_out   <<<16, 256, 0, stream>>>(multi, Wo, bo, out_pre);
    k4c_ln    <<<4, 512, 0, stream>>>(out_pre, gamma, beta, out);
}

// Round 2
// 441.041 us; speedup vs baseline: 1.1375x; 1.1375x over previous
//
#include <hip/hip_runtime.h>
#include <hip/hip_bf16.h>

// MultiHeadAttentionPool3D: B=4, C=256, S=32*32*32=32768, F=512, NH=8, HD=64, Q=4
// Algebra: keys/values [B,F,S] never materialized.
//   scores[b,hq,s] = qW[hq,:]·x[b,:,s] + qb[hq]      (qW = 0.125 * q^T Wk, [32][256])
//   attended[b,hq,:] = Wv·ax[b,hq,:] + bv            (ax = sum_s attn*x, sum attn = 1)
// Round 2: k1 unroll-8 loads + fused chunk stats; k3 fused inline softmax +
// 2 channels/thread + unroll-4; k2a/k2c kernels removed.

#define NHh 8
#define Qq 4
#define Ff 512
#define Cc 256
#define HDd 64
#define HQ 32
#define Ss 32768
#define NCH1 128   // k1 stat chunks (256 s each)
#define NCH3 64    // k3 chunks (512 s each)
#define CH3 512
#define LN_EPSf 1e-5f

// ---------------- K0: fold queries into Wk ----------------
__global__ void k0_prep(const float* __restrict__ q, const float* __restrict__ Wk,
                        const float* __restrict__ bk, float* __restrict__ qWT,
                        float* __restrict__ qb) {
    int hq = blockIdx.x;          // 32 blocks
    int h = hq >> 2, qq = hq & 3;
    int c = threadIdx.x;          // 256 threads
    float acc = 0.f;
    for (int d = 0; d < HDd; ++d)
        acc += q[qq * Ff + h * HDd + d] * Wk[(h * HDd + d) * Cc + c];
    qWT[c * HQ + hq] = acc * 0.125f;   // transposed [c][hq], scale folded
    if (c == 0) {
        float a = 0.f;
        for (int d = 0; d < HDd; ++d) a += q[qq * Ff + h * HDd + d] * bk[h * HDd + d];
        qb[hq] = a * 0.125f;
    }
}

// ------- K1f: scoresT[b][s][hq] = qW·x + qb, fused per-chunk softmax stats -------
__global__ __launch_bounds__(256) void k1_scores(const float* __restrict__ x,
                                                 const float* __restrict__ qWT,
                                                 const float* __restrict__ qb,
                                                 float* __restrict__ scoresT,
                                                 float* __restrict__ pM,
                                                 float* __restrict__ pL) {
    int b = blockIdx.y;
    int ch = blockIdx.x;                       // 128 chunks of 256 s
    int s = ch * 256 + threadIdx.x;
    const float* xb = x + (size_t)b * Cc * Ss + s;
    float acc[HQ];
#pragma unroll
    for (int r = 0; r < HQ; ++r) acc[r] = qb[r];
    const float4* qw4 = (const float4*)qWT;    // uniform -> s_load
    for (int c0 = 0; c0 < Cc; c0 += 8) {
        float xv[8];
#pragma unroll
        for (int k = 0; k < 8; ++k) xv[k] = xb[(size_t)(c0 + k) * Ss];  // 8 loads in flight
#pragma unroll
        for (int k = 0; k < 8; ++k) {
#pragma unroll
            for (int u = 0; u < 8; ++u) {
                float4 w = qw4[(c0 + k) * 8 + u];
                acc[u * 4 + 0] += w.x * xv[k];
                acc[u * 4 + 1] += w.y * xv[k];
                acc[u * 4 + 2] += w.z * xv[k];
                acc[u * 4 + 3] += w.w * xv[k];
            }
        }
    }
    // write scores (overlaps with stats VALU below)
    float4* out4 = (float4*)(scoresT + ((size_t)b * Ss + s) * HQ);
#pragma unroll
    for (int u = 0; u < 8; ++u)
        out4[u] = make_float4(acc[u * 4], acc[u * 4 + 1], acc[u * 4 + 2], acc[u * 4 + 3]);
    // fused per-chunk stats: per row r, max & expsum over this block's 256 s
    int lane = threadIdx.x & 63, wid = threadIdx.x >> 6;
    __shared__ float wm[4][HQ], wl[4][HQ];
#pragma unroll
    for (int r = 0; r < HQ; ++r) {
        float m = acc[r];
#pragma unroll
        for (int o = 1; o < 64; o <<= 1) m = fmaxf(m, __shfl_xor(m, o));
        float e = __expf(acc[r] - m);
#pragma unroll
        for (int o = 1; o < 64; o <<= 1) e += __shfl_xor(e, o);
        if (lane == 0) { wm[wid][r] = m; wl[wid][r] = e; }
    }
    __syncthreads();
    if (threadIdx.x < HQ) {
        int r = threadIdx.x;
        float M2 = fmaxf(fmaxf(wm[0][r], wm[1][r]), fmaxf(wm[2][r], wm[3][r]));
        float L = 0.f;
#pragma unroll
        for (int w = 0; w < 4; ++w) L += wl[w][r] * __expf(wm[w][r] - M2);
        int row = b * HQ + r;
        pM[row * NCH1 + ch] = M2;
        pL[row * NCH1 + ch] = L;
    }
}

// ---------------- K2b: combine chunk stats per row ----------------
__global__ void k2b_combine(const float* __restrict__ pM, const float* __restrict__ pL,
                            float* __restrict__ Mrow, float* __restrict__ iLrow) {
    int row = threadIdx.x;   // 128 threads, 1 block
    float M = -1e30f;
#pragma unroll 4
    for (int ch = 0; ch < NCH1; ++ch) M = fmaxf(M, pM[row * NCH1 + ch]);
    float L = 0.f;
#pragma unroll 4
    for (int ch = 0; ch < NCH1; ++ch)
        L += pL[row * NCH1 + ch] * __expf(pM[row * NCH1 + ch] - M);
    Mrow[row] = M;
    iLrow[row] = 1.f / L;
}

// ------- K3f: inline softmax + partial ax; 2 channels/thread, s-halves -------
__global__ __launch_bounds__(256) void k3_ax(const float* __restrict__ x,
                                             const float* __restrict__ scoresT,
                                             const float* __restrict__ Mrow,
                                             const float* __restrict__ iLrow,
                                             float* __restrict__ part) {
    int b = blockIdx.y, ch = blockIdx.x;   // 64 chunks of 512 s
    int tid = threadIdx.x;
    int h = tid >> 7;                      // 0/1: which 256-s half (wave-uniform)
    int cp = (tid & 127) * 2;              // channel pair
    int s0 = ch * CH3;
    __shared__ float p_lds[CH3 * HQ];      // 64 KB
    // stage p with inline softmax: p = exp(v - M) * iL
    int hq0 = (tid & 7) * 4;               // constant per thread across k
    float4 Mv = *(const float4*)(Mrow + b * HQ + hq0);
    float4 Lv = *(const float4*)(iLrow + b * HQ + hq0);
    const float4* sc4 = (const float4*)(scoresT + ((size_t)b * Ss + s0) * HQ);
    float4* p4 = (float4*)p_lds;
#pragma unroll
    for (int k = 0; k < 16; ++k) {
        int idx = k * 256 + tid;
        float4 v = sc4[idx];
        v.x = __expf(v.x - Mv.x) * Lv.x;
        v.y = __expf(v.y - Mv.y) * Lv.y;
        v.z = __expf(v.z - Mv.z) * Lv.z;
        v.w = __expf(v.w - Mv.w) * Lv.w;
        p4[idx] = v;
    }
    __syncthreads();
    float acc[64];
#pragma unroll
    for (int r = 0; r < 64; ++r) acc[r] = 0.f;
    const float* xb0 = x + ((size_t)b * Cc + cp) * Ss + s0 + h * 256;
    const float* xb1 = xb0 + Ss;
#pragma unroll 4
    for (int j = 0; j < 64; ++j) {
        float4 xa = ((const float4*)xb0)[j];
        float4 xc = ((const float4*)xb1)[j];
#pragma unroll
        for (int e = 0; e < 4; ++e) {
            float xs0 = (e == 0) ? xa.x : (e == 1) ? xa.y : (e == 2) ? xa.z : xa.w;
            float xs1 = (e == 0) ? xc.x : (e == 1) ? xc.y : (e == 2) ? xc.z : xc.w;
            const float4* pr = (const float4*)&p_lds[(h * 256 + j * 4 + e) * HQ];
#pragma unroll
            for (int u = 0; u < 8; ++u) {
                float4 pv = pr[u];
                acc[u * 4 + 0] += pv.x * xs0;
                acc[u * 4 + 1] += pv.y * xs0;
                acc[u * 4 + 2] += pv.z * xs0;
                acc[u * 4 + 3] += pv.w * xs0;
                acc[32 + u * 4 + 0] += pv.x * xs1;
                acc[32 + u * 4 + 1] += pv.y * xs1;
                acc[32 + u * 4 + 2] += pv.z * xs1;
                acc[32 + u * 4 + 3] += pv.w * xs1;
            }
        }
    }
    __syncthreads();
    // combine the two s-halves via LDS (reuse p_lds, padded stride 33)
    if (h == 1) {
#pragma unroll
        for (int r = 0; r < HQ; ++r) {
            p_lds[cp * 33 + r] = acc[r];
            p_lds[(cp + 1) * 33 + r] = acc[32 + r];
        }
    }
    __syncthreads();
    if (h == 0) {
        float* pb = part + ((size_t)(b * NCH3 + ch) * HQ) * Cc + cp;
#pragma unroll
        for (int r = 0; r < HQ; ++r) {
            float2 o = make_float2(acc[r] + p_lds[cp * 33 + r],
                                   acc[32 + r] + p_lds[(cp + 1) * 33 + r]);
            *(float2*)(pb + r * Cc) = o;
        }
    }
}

// ---------------- K3b: reduce partials -> ax[b][hq][c] ----------------
__global__ void k3b_red(const float* __restrict__ part, float* __restrict__ ax) {
    int hq = blockIdx.x, b = blockIdx.y, c = threadIdx.x;
    float s = 0.f;
#pragma unroll 8
    for (int ch = 0; ch < NCH3; ++ch)
        s += part[(((size_t)b * NCH3 + ch) * HQ + hq) * Cc + c];
    ax[((size_t)b * HQ + hq) * Cc + c] = s;
}

// ---------------- K4a: attended -> multi[b][q*512+h*64+d] ----------------
__global__ __launch_bounds__(256) void k4a_att(const float* __restrict__ ax,
                                               const float* __restrict__ Wv,
                                               const float* __restrict__ bv,
                                               float* __restrict__ multi) {
    int b = blockIdx.x, t = threadIdx.x;
    __shared__ float axl[HQ][Cc];
    for (int r = 0; r < HQ; ++r) axl[r][t] = ax[((size_t)b * HQ + r) * Cc + t];
    __syncthreads();
#pragma unroll
    for (int k = 0; k < 8; ++k) {
        int i = k * 256 + t;
        int qq = i >> 9, h = (i >> 6) & 7, d = i & 63;
        int hq = h * 4 + qq, row = h * 64 + d;
        float dot = bv[row];
        const float4* wr = (const float4*)(Wv + row * Cc);
        const float4* ar = (const float4*)&axl[hq][0];
        for (int c4 = 0; c4 < Cc / 4; ++c4) {
            float4 w = wr[c4], a = ar[c4];
            dot += w.x * a.x + w.y * a.y + w.z * a.z + w.w * a.w;
        }
        multi[b * 2048 + i] = dot;   // [B, Q*F] with index q*512 + h*64 + d
    }
}

// ---------------- K4b: out_pre[b][f] = multi[b]·Wo[f] + bo[f] ----------------
__global__ __launch_bounds__(256) void k4b_out(const float* __restrict__ multi,
                                               const float* __restrict__ Wo,
                                               const float* __restrict__ bo,
                                               float* __restrict__ out_pre) {
    int fc = blockIdx.x;   // 16 blocks * 32 f each
    int t = threadIdx.x;
    int fl = t >> 3, jo = t & 7;
    int f = fc * 32 + fl;
    __shared__ float ml[4][2048];
    for (int k = 0; k < 32; ++k) {
        int idx = k * 256 + t;
        ml[idx >> 11][idx & 2047] = multi[idx];
    }
    __syncthreads();
    float acc[4] = {0.f, 0.f, 0.f, 0.f};
    const float4* wr = (const float4*)(Wo + (size_t)f * 2048 + jo * 256);
    for (int jj = 0; jj < 64; ++jj) {
        float4 w = wr[jj];
#pragma unroll
        for (int bb = 0; bb < 4; ++bb) {
            const float4* m4 = (const float4*)&ml[bb][jo * 256];
            float4 m = m4[jj];
            acc[bb] += w.x * m.x + w.y * m.y + w.z * m.z + w.w * m.w;
        }
    }
#pragma unroll
    for (int o = 1; o < 8; o <<= 1) {
#pragma unroll
        for (int bb = 0; bb < 4; ++bb) acc[bb] += __shfl_xor(acc[bb], o);
    }
    if (jo == 0) {
#pragma unroll
        for (int bb = 0; bb < 4; ++bb) out_pre[bb * Ff + f] = acc[bb] + bo[f];
    }
}

// ---------------- K4c: LayerNorm over F=512 ----------------
__global__ __launch_bounds__(512) void k4c_ln(const float* __restrict__ out_pre,
                                              const float* __restrict__ gamma,
                                              const float* __restrict__ beta,
                                              float* __restrict__ out) {
    int b = blockIdx.x, t = threadIdx.x;
    float v = out_pre[b * Ff + t];
    float s = v;
#pragma unroll
    for (int o = 1; o < 64; o <<= 1) s += __shfl_xor(s, o);
    __shared__ float red[8], red2[8];
    int w = t >> 6;
    if ((t & 63) == 0) red[w] = s;
    __syncthreads();
    float mu = 0.f;
#pragma unroll
    for (int ww = 0; ww < 8; ++ww) mu += red[ww];
    mu *= (1.f / Ff);
    float d = v - mu;
    float s2 = d * d;
#pragma unroll
    for (int o = 1; o < 64; o <<= 1) s2 += __shfl_xor(s2, o);
    if ((t & 63) == 0) red2[w] = s2;
    __syncthreads();
    float var = 0.f;
#pragma unroll
    for (int ww = 0; ww < 8; ++ww) var += red2[ww];
    var *= (1.f / Ff);
    out[b * Ff + t] = d * rsqrtf(var + LN_EPSf) * gamma[t] + beta[t];
}

extern "C" void kernel_launch(void* const* d_in, const int* in_sizes, int n_in,
                              void* d_out, int out_size, void* d_ws, size_t ws_size,
                              hipStream_t stream) {
    const float* x       = (const float*)d_in[0];
    const float* queries = (const float*)d_in[1];
    const float* Wk      = (const float*)d_in[2];
    const float* bk      = (const float*)d_in[3];
    const float* Wv      = (const float*)d_in[4];
    const float* bv      = (const float*)d_in[5];
    const float* Wo      = (const float*)d_in[6];
    const float* bo      = (const float*)d_in[7];
    const float* gamma   = (const float*)d_in[8];
    const float* beta    = (const float*)d_in[9];
    float* out = (float*)d_out;
    float* ws  = (float*)d_ws;

    // ws layout (floats); total ~25.6 MB
    float* qWT     = ws;                  // 8192
    float* qb      = ws + 8192;           // 32
    float* Mrow    = ws + 8224;           // 128
    float* iLrow   = ws + 8352;           // 128
    float* pM      = ws + 8480;           // 16384 (128 rows x 128 chunks)
    float* pL      = ws + 24864;          // 16384
    float* multi   = ws + 41248;          // 8192
    float* out_pre = ws + 49440;          // 2048
    float* scoresT = ws + 65536;          // 4,194,304
    float* part    = ws + 65536 + 4194304;          // 2,097,152
    float* ax      = ws + 65536 + 4194304 + 2097152; // 32768

    k0_prep    <<<32, 256, 0, stream>>>(queries, Wk, bk, qWT, qb);
    k1_scores  <<<dim3(NCH1, 4), 256, 0, stream>>>(x, qWT, qb, scoresT, pM, pL);
    k2b_combine<<<1, 128, 0, stream>>>(pM, pL, Mrow, iLrow);
    k3_ax      <<<dim3(NCH3, 4), 256, 0, stream>>>(x, scoresT, Mrow, iLrow, part);
    k3b_red    <<<dim3(HQ, 4), 256, 0, stream>>>(part, ax);
    k4a_att    <<<4, 256, 0, stream>>>(ax, Wv, bv, multi);
    k4b_out    <<<16, 256, 0, stream>>>(multi, Wo, bo, out_pre);
    k4c_ln     <<<4, 512, 0, stream>>>(out_pre, gamma, beta, out);
}

// Round 4
// 417.732 us; speedup vs baseline: 1.2010x; 1.0558x over previous
//
#include <hip/hip_runtime.h>
#include <hip/hip_bf16.h>

// MultiHeadAttentionPool3D: B=4, C=256, S=32768, F=512, NH=8, HD=64, Q=4
// Algebra: keys/values [B,F,S] never materialized.
//   scores[b,hq,s] = qW[hq,:]·x[b,:,s] + qb[hq]      (qW = 0.125 * q^T Wk)
//   attended[b,hq,:] = Wv·ax[b,hq,:] + bv            (ax = sum_s attn*x; sum attn = 1)
// Round 3 (resubmit after infra timeout): k1/k3 rebuilt around LDS-staged x tiles
// (1KB-contiguous global reads, reg-staged prefetch); scores stored row-major
// [b][32][S]; k3 register-tiled from LDS with per-chunk LDS-atomic accumulation.

#define Ff 512
#define Cc 256
#define HQ 32
#define Ss 32768
#define NCH1 128   // s-blocks of 256
#define LN_EPSf 1e-5f

// ---------------- K0: fold queries into Wk ----------------
__global__ void k0_prep(const float* __restrict__ q, const float* __restrict__ Wk,
                        const float* __restrict__ bk, float* __restrict__ qWT,
                        float* __restrict__ qb) {
    int hq = blockIdx.x;          // 32 blocks
    int h = hq >> 2, qq = hq & 3;
    int c = threadIdx.x;          // 256 threads
    float acc = 0.f;
    for (int d = 0; d < 64; ++d)
        acc += q[qq * Ff + h * 64 + d] * Wk[(h * 64 + d) * Cc + c];
    qWT[c * HQ + hq] = acc * 0.125f;   // [c][hq], scale folded
    if (c == 0) {
        float a = 0.f;
        for (int d = 0; d < 64; ++d) a += q[qq * Ff + h * 64 + d] * bk[h * 64 + d];
        qb[hq] = a * 0.125f;
    }
}

// ------- K1: scoresT[b][r][s] = qW·x + qb, fused per-block softmax stats -------
// Block: (sb, b) -> s-tile of 256. Wave w owns rows 8w..8w+7, lane owns 4 s.
__global__ __launch_bounds__(256) void k1_scores(const float* __restrict__ x,
                                                 const float* __restrict__ qWT,
                                                 const float* __restrict__ qb,
                                                 float* __restrict__ scoresT,
                                                 float* __restrict__ pM,
                                                 float* __restrict__ pL) {
    int b = blockIdx.y, sb = blockIdx.x;
    int s0 = sb * 256;
    int t = threadIdx.x;
    int w = t >> 6, l = t & 63;
    __shared__ float xs[16][260];       // c-chunk tile, pad 260 for bank spread
    __shared__ float qls[Cc * HQ];      // full qW table, 32 KB
#pragma unroll
    for (int k = 0; k < 8; ++k)
        ((float4*)qls)[t + 256 * k] = ((const float4*)qWT)[t + 256 * k];

    const float* xbase = x + (size_t)b * Cc * Ss + s0;
    // register-stage chunk 0 (16 rows x 1KB contiguous each)
    float4 st0, st1, st2, st3;
    {
        int g;
        g = t;       st0 = *(const float4*)(xbase + (size_t)(g >> 6) * Ss + (g & 63) * 4);
        g = t + 256; st1 = *(const float4*)(xbase + (size_t)(g >> 6) * Ss + (g & 63) * 4);
        g = t + 512; st2 = *(const float4*)(xbase + (size_t)(g >> 6) * Ss + (g & 63) * 4);
        g = t + 768; st3 = *(const float4*)(xbase + (size_t)(g >> 6) * Ss + (g & 63) * 4);
    }
    float acc[8][4];
#pragma unroll
    for (int ri = 0; ri < 8; ++ri) {
        float qq = qb[w * 8 + ri];
        acc[ri][0] = qq; acc[ri][1] = qq; acc[ri][2] = qq; acc[ri][3] = qq;
    }
    __syncthreads();   // qls ready

    for (int c0 = 0; c0 < Cc; c0 += 16) {
        {   // commit staged regs to LDS
            int g;
            g = t;       *(float4*)&xs[g >> 6][(g & 63) * 4] = st0;
            g = t + 256; *(float4*)&xs[g >> 6][(g & 63) * 4] = st1;
            g = t + 512; *(float4*)&xs[g >> 6][(g & 63) * 4] = st2;
            g = t + 768; *(float4*)&xs[g >> 6][(g & 63) * 4] = st3;
        }
        __syncthreads();
        if (c0 + 16 < Cc) {   // prefetch next chunk during compute
            int g;
            g = t;       st0 = *(const float4*)(xbase + (size_t)(c0 + 16 + (g >> 6)) * Ss + (g & 63) * 4);
            g = t + 256; st1 = *(const float4*)(xbase + (size_t)(c0 + 16 + (g >> 6)) * Ss + (g & 63) * 4);
            g = t + 512; st2 = *(const float4*)(xbase + (size_t)(c0 + 16 + (g >> 6)) * Ss + (g & 63) * 4);
            g = t + 768; st3 = *(const float4*)(xbase + (size_t)(c0 + 16 + (g >> 6)) * Ss + (g & 63) * 4);
        }
#pragma unroll 4
        for (int c = 0; c < 16; ++c) {
            float xv0 = xs[c][l], xv1 = xs[c][l + 64];
            float xv2 = xs[c][l + 128], xv3 = xs[c][l + 192];
            float4 q0 = *(const float4*)&qls[(c0 + c) * HQ + w * 8];
            float4 q1 = *(const float4*)&qls[(c0 + c) * HQ + w * 8 + 4];
            float qwv[8] = {q0.x, q0.y, q0.z, q0.w, q1.x, q1.y, q1.z, q1.w};
#pragma unroll
            for (int ri = 0; ri < 8; ++ri) {
                acc[ri][0] += qwv[ri] * xv0;
                acc[ri][1] += qwv[ri] * xv1;
                acc[ri][2] += qwv[ri] * xv2;
                acc[ri][3] += qwv[ri] * xv3;
            }
        }
        __syncthreads();   // compute done before next chunk overwrite
    }
    // coalesced row-major stores: scoresT[b][r][s]
    float* srow = scoresT + ((size_t)b * HQ + w * 8) * Ss + s0 + l;
#pragma unroll
    for (int ri = 0; ri < 8; ++ri) {
        srow[(size_t)ri * Ss]       = acc[ri][0];
        srow[(size_t)ri * Ss + 64]  = acc[ri][1];
        srow[(size_t)ri * Ss + 128] = acc[ri][2];
        srow[(size_t)ri * Ss + 192] = acc[ri][3];
    }
    // fused per-block stats: row lives entirely in this wave
#pragma unroll
    for (int ri = 0; ri < 8; ++ri) {
        float m = fmaxf(fmaxf(acc[ri][0], acc[ri][1]), fmaxf(acc[ri][2], acc[ri][3]));
#pragma unroll
        for (int o = 1; o < 64; o <<= 1) m = fmaxf(m, __shfl_xor(m, o));
        float e = __expf(acc[ri][0] - m) + __expf(acc[ri][1] - m) +
                  __expf(acc[ri][2] - m) + __expf(acc[ri][3] - m);
#pragma unroll
        for (int o = 1; o < 64; o <<= 1) e += __shfl_xor(e, o);
        if (l == 0) {
            int row = b * HQ + w * 8 + ri;
            pM[row * NCH1 + sb] = m;
            pL[row * NCH1 + sb] = e;
        }
    }
}

// ---------------- K2b: combine chunk stats per row ----------------
__global__ void k2b_combine(const float* __restrict__ pM, const float* __restrict__ pL,
                            float* __restrict__ Mrow, float* __restrict__ iLrow) {
    int row = threadIdx.x;   // 128 threads, 1 block
    float M = -1e30f;
#pragma unroll 4
    for (int ch = 0; ch < NCH1; ++ch) M = fmaxf(M, pM[row * NCH1 + ch]);
    float L = 0.f;
#pragma unroll 4
    for (int ch = 0; ch < NCH1; ++ch)
        L += pL[row * NCH1 + ch] * __expf(pM[row * NCH1 + ch] - M);
    Mrow[row] = M;
    iLrow[row] = 1.f / L;
}

// ------- K3: partial ax; p-tile in LDS (inline softmax), x staged per c-chunk -------
// Block: (sb, b) s-tile 256. Wave w owns s-quarter; lane owns 2r x 2c register tile.
__global__ __launch_bounds__(256) void k3_ax(const float* __restrict__ x,
                                             const float* __restrict__ scoresT,
                                             const float* __restrict__ Mrow,
                                             const float* __restrict__ iLrow,
                                             float* __restrict__ part) {
    int b = blockIdx.y, sb = blockIdx.x;
    int s0 = sb * 256;
    int t = threadIdx.x, w = t >> 6, l = t & 63;
    __shared__ float pT[HQ][260];   // normalized p, row-major
    __shared__ float xls[8][260];   // c-chunk of x
    __shared__ float axs[HQ][256];  // per-block ax accumulator
#pragma unroll
    for (int k = 0; k < 8; ++k)
        ((float4*)axs)[t + 256 * k] = make_float4(0.f, 0.f, 0.f, 0.f);
    // stage + normalize p (coalesced from row-major scoresT)
#pragma unroll
    for (int k = 0; k < 8; ++k) {
        int g = t + 256 * k;
        int r = g >> 6, col4 = g & 63;
        int row = b * HQ + r;
        float M = Mrow[row], iL = iLrow[row];
        float4 v = *(const float4*)(scoresT + (size_t)row * Ss + s0 + col4 * 4);
        v.x = __expf(v.x - M) * iL; v.y = __expf(v.y - M) * iL;
        v.z = __expf(v.z - M) * iL; v.w = __expf(v.w - M) * iL;
        *(float4*)&pT[r][col4 * 4] = v;
    }
    const float* xbase = x + (size_t)b * Cc * Ss + s0;
    float4 st0, st1;   // reg-stage chunk 0 (8 rows x 1KB)
    {
        int g;
        g = t;       st0 = *(const float4*)(xbase + (size_t)(g >> 6) * Ss + (g & 63) * 4);
        g = t + 256; st1 = *(const float4*)(xbase + (size_t)(g >> 6) * Ss + (g & 63) * 4);
    }
    int rp = l & 15, cp = l >> 4;
    __syncthreads();   // pT + axs ready

    for (int c0 = 0; c0 < Cc; c0 += 8) {
        {
            int g;
            g = t;       *(float4*)&xls[g >> 6][(g & 63) * 4] = st0;
            g = t + 256; *(float4*)&xls[g >> 6][(g & 63) * 4] = st1;
        }
        __syncthreads();
        if (c0 + 8 < Cc) {
            int g;
            g = t;       st0 = *(const float4*)(xbase + (size_t)(c0 + 8 + (g >> 6)) * Ss + (g & 63) * 4);
            g = t + 256; st1 = *(const float4*)(xbase + (size_t)(c0 + 8 + (g >> 6)) * Ss + (g & 63) * 4);
        }
        float a00 = 0.f, a01 = 0.f, a10 = 0.f, a11 = 0.f;
#pragma unroll 4
        for (int j = 0; j < 16; ++j) {
            int s4 = (w * 16 + j) * 4;
            float4 p0 = *(const float4*)&pT[rp][s4];
            float4 p1 = *(const float4*)&pT[rp + 16][s4];
            float4 x0 = *(const float4*)&xls[cp * 2][s4];
            float4 x1 = *(const float4*)&xls[cp * 2 + 1][s4];
            a00 += p0.x * x0.x + p0.y * x0.y + p0.z * x0.z + p0.w * x0.w;
            a01 += p0.x * x1.x + p0.y * x1.y + p0.z * x1.z + p0.w * x1.w;
            a10 += p1.x * x0.x + p1.y * x0.y + p1.z * x0.z + p1.w * x0.w;
            a11 += p1.x * x1.x + p1.y * x1.y + p1.z * x1.z + p1.w * x1.w;
        }
        atomicAdd(&axs[rp][c0 + cp * 2],          a00);
        atomicAdd(&axs[rp][c0 + cp * 2 + 1],      a01);
        atomicAdd(&axs[rp + 16][c0 + cp * 2],     a10);
        atomicAdd(&axs[rp + 16][c0 + cp * 2 + 1], a11);
        __syncthreads();   // flush + compute done before next overwrite
    }
    float* pb = part + (size_t)(b * NCH1 + sb) * (HQ * Cc);
#pragma unroll
    for (int k = 0; k < 8; ++k)
        ((float4*)pb)[t + 256 * k] = ((const float4*)axs)[t + 256 * k];
}

// ---------------- K3b: reduce partials over 128 s-blocks ----------------
__global__ __launch_bounds__(256) void k3b_red(const float* __restrict__ part,
                                               float* __restrict__ ax) {
    int r = blockIdx.x, b = blockIdx.y, c = threadIdx.x;
    const float* p = part + (size_t)b * NCH1 * (HQ * Cc) + r * Cc + c;
    float s = 0.f;
#pragma unroll 16
    for (int j = 0; j < NCH1; ++j) s += p[(size_t)j * (HQ * Cc)];
    ax[((size_t)b * HQ + r) * Cc + c] = s;
}

// ---------------- K4a: attended -> multi[b][q*512+h*64+d] ----------------
__global__ __launch_bounds__(256) void k4a_att(const float* __restrict__ ax,
                                               const float* __restrict__ Wv,
                                               const float* __restrict__ bv,
                                               float* __restrict__ multi) {
    int b = blockIdx.y, fc = blockIdx.x;   // 8 x 4 grid
    int t = threadIdx.x;
    int i = fc * 256 + t;
    int qq = i >> 9, h = (i >> 6) & 7, d = i & 63;
    int hq = h * 4 + qq, row = h * 64 + d;
    const float4* wr = (const float4*)(Wv + (size_t)row * Cc);
    const float4* ar = (const float4*)(ax + ((size_t)b * HQ + hq) * Cc);
    float dot = bv[row];
#pragma unroll 8
    for (int c4 = 0; c4 < 64; ++c4) {
        float4 wv = wr[c4], av = ar[c4];
        dot += wv.x * av.x + wv.y * av.y + wv.z * av.z + wv.w * av.w;
    }
    multi[b * 2048 + i] = dot;
}

// ---------------- K4b: out_pre[b][f] = multi[b]·Wo[f] + bo[f] ----------------
__global__ __launch_bounds__(256) void k4b_out(const float* __restrict__ multi,
                                               const float* __restrict__ Wo,
                                               const float* __restrict__ bo,
                                               float* __restrict__ out_pre) {
    int fc = blockIdx.x;   // 16 blocks * 32 f each
    int t = threadIdx.x;
    int fl = t >> 3, jo = t & 7;
    int f = fc * 32 + fl;
    __shared__ float ml[4][2048];
    for (int k = 0; k < 32; ++k) {
        int idx = k * 256 + t;
        ml[idx >> 11][idx & 2047] = multi[idx];
    }
    __syncthreads();
    float acc[4] = {0.f, 0.f, 0.f, 0.f};
    const float4* wr = (const float4*)(Wo + (size_t)f * 2048 + jo * 256);
    for (int jj = 0; jj < 64; ++jj) {
        float4 wv = wr[jj];
#pragma unroll
        for (int bb = 0; bb < 4; ++bb) {
            const float4* m4 = (const float4*)&ml[bb][jo * 256];
            float4 m = m4[jj];
            acc[bb] += wv.x * m.x + wv.y * m.y + wv.z * m.z + wv.w * m.w;
        }
    }
#pragma unroll
    for (int o = 1; o < 8; o <<= 1) {
#pragma unroll
        for (int bb = 0; bb < 4; ++bb) acc[bb] += __shfl_xor(acc[bb], o);
    }
    if (jo == 0) {
#pragma unroll
        for (int bb = 0; bb < 4; ++bb) out_pre[bb * Ff + f] = acc[bb] + bo[f];
    }
}

// ---------------- K4c: LayerNorm over F=512 ----------------
__global__ __launch_bounds__(512) void k4c_ln(const float* __restrict__ out_pre,
                                              const float* __restrict__ gamma,
                                              const float* __restrict__ beta,
                                              float* __restrict__ out) {
    int b = blockIdx.x, t = threadIdx.x;
    float v = out_pre[b * Ff + t];
    float s = v;
#pragma unroll
    for (int o = 1; o < 64; o <<= 1) s += __shfl_xor(s, o);
    __shared__ float red[8], red2[8];
    int w = t >> 6;
    if ((t & 63) == 0) red[w] = s;
    __syncthreads();
    float mu = 0.f;
#pragma unroll
    for (int ww = 0; ww < 8; ++ww) mu += red[ww];
    mu *= (1.f / Ff);
    float d = v - mu;
    float s2 = d * d;
#pragma unroll
    for (int o = 1; o < 64; o <<= 1) s2 += __shfl_xor(s2, o);
    if ((t & 63) == 0) red2[w] = s2;
    __syncthreads();
    float var = 0.f;
#pragma unroll
    for (int ww = 0; ww < 8; ++ww) var += red2[ww];
    var *= (1.f / Ff);
    out[b * Ff + t] = d * rsqrtf(var + LN_EPSf) * gamma[t] + beta[t];
}

extern "C" void kernel_launch(void* const* d_in, const int* in_sizes, int n_in,
                              void* d_out, int out_size, void* d_ws, size_t ws_size,
                              hipStream_t stream) {
    const float* x       = (const float*)d_in[0];
    const float* queries = (const float*)d_in[1];
    const float* Wk      = (const float*)d_in[2];
    const float* bk      = (const float*)d_in[3];
    const float* Wv      = (const float*)d_in[4];
    const float* bv      = (const float*)d_in[5];
    const float* Wo      = (const float*)d_in[6];
    const float* bo      = (const float*)d_in[7];
    const float* gamma   = (const float*)d_in[8];
    const float* beta    = (const float*)d_in[9];
    float* out = (float*)d_out;
    float* ws  = (float*)d_ws;

    // ws layout (floats); total ~34 MB
    float* qWT     = ws;                  // 8192
    float* qb      = ws + 8192;           // 32
    float* Mrow    = ws + 8224;           // 128
    float* iLrow   = ws + 8352;           // 128
    float* pM      = ws + 8480;           // 16384
    float* pL      = ws + 24864;          // 16384
    float* multi   = ws + 41248;          // 8192
    float* out_pre = ws + 49440;          // 2048
    float* ax      = ws + 51488;          // 32768
    float* scoresT = ws + 98304;                     // 4,194,304  [b][32][S]
    float* part    = ws + 98304 + 4194304;           // 4,194,304  [b][128][32][256]

    k0_prep    <<<32, 256, 0, stream>>>(queries, Wk, bk, qWT, qb);
    k1_scores  <<<dim3(NCH1, 4), 256, 0, stream>>>(x, qWT, qb, scoresT, pM, pL);
    k2b_combine<<<1, 128, 0, stream>>>(pM, pL, Mrow, iLrow);
    k3_ax      <<<dim3(NCH1, 4), 256, 0, stream>>>(x, scoresT, Mrow, iLrow, part);
    k3b_red    <<<dim3(HQ, 4), 256, 0, stream>>>(part, ax);
    k4a_att    <<<dim3(8, 4), 256, 0, stream>>>(ax, Wv, bv, multi);
    k4b_out    <<<16, 256, 0, stream>>>(multi, Wo, bo, out_pre);
    k4c_ln     <<<4, 512, 0, stream>>>(out_pre, gamma, beta, out);
}

// Round 5
// 274.911 us; speedup vs baseline: 1.8249x; 1.5195x over previous
//
#include <hip/hip_runtime.h>
#include <hip/hip_bf16.h>

// MultiHeadAttentionPool3D: B=4, C=256, S=32768, F=512, NH=8, HD=64, Q=4
// Algebra: keys/values [B,F,S] never materialized.
//   scores[b,hq,s] = qW[hq,:]·x[b,:,s] + qb[hq]      (qW = 0.125 * q^T Wk)
//   attended[b,hq,:] = Wv·ax[b,hq,:] + bv            (ax = sum_s attn*x; sum attn = 1)
// Round 5: k1/k3 use MFMA 16x16x32 bf16. Layout-permutation-safe frag loading:
// A and B both use lane&15 for m/n and the SAME positional k-mapping (k=8g+j),
// so the reduction is correct for any HW k-permutation. C/D: col=lane&15,
// row=(lane>>4)*4+reg (HW-verified). k4b re-gridded, k2b parallelized.

#define Ff 512
#define Cc 256
#define HQ 32
#define Ss 32768
#define NCH1 128   // s-blocks of 256
#define LN_EPSf 1e-5f

typedef __attribute__((ext_vector_type(8))) short bf16x8;
typedef __attribute__((ext_vector_type(4))) float f32x4;

__device__ __forceinline__ ushort f2bf(float f) {   // RNE truncate to bf16
    unsigned int b = __float_as_uint(f);
    b += 0x7fffu + ((b >> 16) & 1u);
    return (ushort)(b >> 16);
}

// ---------------- K0: fold queries into Wk -> bf16 qW [32][256] ----------------
__global__ void k0_prep(const float* __restrict__ q, const float* __restrict__ Wk,
                        const float* __restrict__ bk, ushort* __restrict__ qWbf,
                        float* __restrict__ qb) {
    int hq = blockIdx.x;          // 32 blocks
    int h = hq >> 2, qq = hq & 3;
    int c = threadIdx.x;          // 256 threads
    float acc = 0.f;
    for (int d = 0; d < 64; ++d)
        acc += q[qq * Ff + h * 64 + d] * Wk[(h * 64 + d) * Cc + c];
    qWbf[hq * Cc + c] = f2bf(acc * 0.125f);   // row-major [r][c]
    if (c == 0) {
        float a = 0.f;
        for (int d = 0; d < 64; ++d) a += q[qq * Ff + h * 64 + d] * bk[h * 64 + d];
        qb[hq] = a * 0.125f;
    }
}

// ------- K1: scoresT[b][r][s] = qW·x + qb via MFMA, fused per-block stats -------
// Block (sb,b): s-tile 256. Wave w owns s in [w*64, w*64+64) = 4 n-tiles.
// M=r (2 m-tiles), N=s, K=c (4 chunks of 64 staged in LDS, 2 k-steps each).
__global__ __launch_bounds__(256) void k1_scores(const float* __restrict__ x,
                                                 const ushort* __restrict__ qWbf,
                                                 const float* __restrict__ qb,
                                                 float* __restrict__ scoresT,
                                                 float* __restrict__ pM,
                                                 float* __restrict__ pL) {
    int b = blockIdx.y, sb = blockIdx.x;
    int s0 = sb * 256;
    int t = threadIdx.x;
    int w = t >> 6, l = t & 63, lg = l >> 4, ln = l & 15;
    __shared__ ushort qls[HQ][264];    // qW bf16, padded (row byte-stride 528, 16B-mult)
    __shared__ ushort xls[64][264];    // x c-chunk bf16
    __shared__ float wm[4][HQ], wl[4][HQ];

    // stage qW: 8192 ushorts = 1024 x ushort8, 4 per thread
#pragma unroll
    for (int k = 0; k < 4; ++k) {
        int idx = t + 256 * k;
        int row = idx >> 5, col8 = idx & 31;
        *(bf16x8*)&qls[row][col8 * 8] = *(const bf16x8*)(qWbf + row * Cc + col8 * 8);
    }
    // stage x chunk 0: 64 rows x 256 s, fp32->bf16
    const float* xbase = x + (size_t)b * Cc * Ss + s0;
#pragma unroll
    for (int k = 0; k < 16; ++k) {
        int row = w + 4 * k;          // wave-uniform row
        float4 v = *(const float4*)(xbase + (size_t)row * Ss + l * 4);
        ushort4 u; u.x = f2bf(v.x); u.y = f2bf(v.y); u.z = f2bf(v.z); u.w = f2bf(v.w);
        *(ushort4*)&xls[row][l * 4] = u;
    }
    // acc init with bias: acc[mt][nt][reg], row = mt*16 + lg*4 + reg
    f32x4 acc[2][4];
#pragma unroll
    for (int mt = 0; mt < 2; ++mt) {
        f32x4 iv;
#pragma unroll
        for (int reg = 0; reg < 4; ++reg) iv[reg] = qb[mt * 16 + lg * 4 + reg];
#pragma unroll
        for (int nt = 0; nt < 4; ++nt) acc[mt][nt] = iv;
    }
    __syncthreads();

    for (int cc = 0; cc < 4; ++cc) {
#pragma unroll
        for (int ksl = 0; ksl < 2; ++ksl) {
            // A-frags: qW[r = mt*16+ln][c = (cc*2+ksl)*32 + lg*8 + j]  (b128)
            bf16x8 pa0 = *(const bf16x8*)&qls[ln]     [(cc * 2 + ksl) * 32 + lg * 8];
            bf16x8 pa1 = *(const bf16x8*)&qls[16 + ln][(cc * 2 + ksl) * 32 + lg * 8];
#pragma unroll
            for (int nt = 0; nt < 4; ++nt) {
                int sloc = w * 64 + nt * 16 + ln;
                // B-frag: x[c = ksl*32 + lg*8 + j][s = sloc]  (same k-mapping as A)
                bf16x8 bv;
#pragma unroll
                for (int j = 0; j < 8; ++j)
                    bv[j] = (short)xls[ksl * 32 + lg * 8 + j][sloc];
                acc[0][nt] = __builtin_amdgcn_mfma_f32_16x16x32_bf16(pa0, bv, acc[0][nt], 0, 0, 0);
                acc[1][nt] = __builtin_amdgcn_mfma_f32_16x16x32_bf16(pa1, bv, acc[1][nt], 0, 0, 0);
            }
        }
        __syncthreads();   // reads of xls done
        if (cc < 3) {
#pragma unroll
            for (int k = 0; k < 16; ++k) {
                int row = w + 4 * k;
                float4 v = *(const float4*)(xbase + (size_t)((cc + 1) * 64 + row) * Ss + l * 4);
                ushort4 u; u.x = f2bf(v.x); u.y = f2bf(v.y); u.z = f2bf(v.z); u.w = f2bf(v.w);
                *(ushort4*)&xls[row][l * 4] = u;
            }
        }
        __syncthreads();   // next chunk visible
    }

    // stores: scoresT[b][row][s], row = mt*16+lg*4+reg, s = s0 + w*64 + nt*16 + ln
#pragma unroll
    for (int mt = 0; mt < 2; ++mt)
#pragma unroll
    for (int nt = 0; nt < 4; ++nt)
#pragma unroll
    for (int reg = 0; reg < 4; ++reg)
        scoresT[(size_t)(b * HQ + mt * 16 + lg * 4 + reg) * Ss + s0 + w * 64 + nt * 16 + ln]
            = acc[mt][nt][reg];

    // per-wave row stats (rows live in 16-lane groups; shfl_xor 1..8 stays in-group)
#pragma unroll
    for (int mt = 0; mt < 2; ++mt)
#pragma unroll
    for (int reg = 0; reg < 4; ++reg) {
        float m = fmaxf(fmaxf(acc[mt][0][reg], acc[mt][1][reg]),
                        fmaxf(acc[mt][2][reg], acc[mt][3][reg]));
#pragma unroll
        for (int o = 1; o < 16; o <<= 1) m = fmaxf(m, __shfl_xor(m, o));
        float e = 0.f;
#pragma unroll
        for (int nt = 0; nt < 4; ++nt) e += __expf(acc[mt][nt][reg] - m);
#pragma unroll
        for (int o = 1; o < 16; o <<= 1) e += __shfl_xor(e, o);
        if (ln == 0) {
            int row = mt * 16 + lg * 4 + reg;
            wm[w][row] = m; wl[w][row] = e;
        }
    }
    __syncthreads();
    if (t < HQ) {
        float M2 = fmaxf(fmaxf(wm[0][t], wm[1][t]), fmaxf(wm[2][t], wm[3][t]));
        float L = 0.f;
#pragma unroll
        for (int ww = 0; ww < 4; ++ww) L += wl[ww][t] * __expf(wm[ww][t] - M2);
        pM[(b * HQ + t) * NCH1 + sb] = M2;
        pL[(b * HQ + t) * NCH1 + sb] = L;
    }
}

// ---------------- K2b: combine chunk stats per row (1 block/row) ----------------
__global__ void k2b_combine(const float* __restrict__ pM, const float* __restrict__ pL,
                            float* __restrict__ Mrow, float* __restrict__ iLrow) {
    int row = blockIdx.x;   // 128 blocks x 64 threads
    int l = threadIdx.x;
    float m0 = pM[row * NCH1 + l], m1 = pM[row * NCH1 + 64 + l];
    float m = fmaxf(m0, m1);
#pragma unroll
    for (int o = 1; o < 64; o <<= 1) m = fmaxf(m, __shfl_xor(m, o));
    float e = pL[row * NCH1 + l] * __expf(m0 - m) + pL[row * NCH1 + 64 + l] * __expf(m1 - m);
#pragma unroll
    for (int o = 1; o < 64; o <<= 1) e += __shfl_xor(e, o);
    if (l == 0) { Mrow[row] = m; iLrow[row] = 1.f / e; }
}

// ------- K3: partial ax[b][sb][32][256] via MFMA: A=p (M=r), B=x (K=s, N=c) -------
// Block (sb,b): s-tile 256 = K. Wave w owns n-tile w of each 64-c chunk.
__global__ __launch_bounds__(256) void k3_ax(const float* __restrict__ x,
                                             const float* __restrict__ scoresT,
                                             const float* __restrict__ Mrow,
                                             const float* __restrict__ iLrow,
                                             float* __restrict__ part) {
    int b = blockIdx.y, sb = blockIdx.x;
    int s0 = sb * 256;
    int t = threadIdx.x;
    int w = t >> 6, l = t & 63, lg = l >> 4, ln = l & 15;
    __shared__ ushort pls[HQ][264];    // normalized p, bf16
    __shared__ ushort xls[64][264];    // x c-chunk bf16

    // stage + normalize p: wave w does rows 8w..8w+7
#pragma unroll
    for (int k = 0; k < 8; ++k) {
        int row = w * 8 + k;           // wave-uniform
        float M = Mrow[b * HQ + row], iL = iLrow[b * HQ + row];
        float4 v = *(const float4*)(scoresT + (size_t)(b * HQ + row) * Ss + s0 + l * 4);
        ushort4 u;
        u.x = f2bf(__expf(v.x - M) * iL); u.y = f2bf(__expf(v.y - M) * iL);
        u.z = f2bf(__expf(v.z - M) * iL); u.w = f2bf(__expf(v.w - M) * iL);
        *(ushort4*)&pls[row][l * 4] = u;
    }
    // stage x chunk 0
    const float* xbase = x + (size_t)b * Cc * Ss + s0;
#pragma unroll
    for (int k = 0; k < 16; ++k) {
        int row = w + 4 * k;
        float4 v = *(const float4*)(xbase + (size_t)row * Ss + l * 4);
        ushort4 u; u.x = f2bf(v.x); u.y = f2bf(v.y); u.z = f2bf(v.z); u.w = f2bf(v.w);
        *(ushort4*)&xls[row][l * 4] = u;
    }
    __syncthreads();

    for (int cc = 0; cc < 4; ++cc) {
        f32x4 acc0 = {0.f, 0.f, 0.f, 0.f}, acc1 = {0.f, 0.f, 0.f, 0.f};
#pragma unroll
        for (int ks = 0; ks < 8; ++ks) {
            // A-frags: p[r = mt*16+ln][s = ks*32 + lg*8 + j]
            bf16x8 pa0 = *(const bf16x8*)&pls[ln]     [ks * 32 + lg * 8];
            bf16x8 pa1 = *(const bf16x8*)&pls[16 + ln][ks * 32 + lg * 8];
            // B-frag: x[c = w*16+ln][s = ks*32 + lg*8 + j]  (same k-mapping)
            bf16x8 bv = *(const bf16x8*)&xls[w * 16 + ln][ks * 32 + lg * 8];
            acc0 = __builtin_amdgcn_mfma_f32_16x16x32_bf16(pa0, bv, acc0, 0, 0, 0);
            acc1 = __builtin_amdgcn_mfma_f32_16x16x32_bf16(pa1, bv, acc1, 0, 0, 0);
        }
        // write: part[b][sb][row][c], row = mt*16+lg*4+reg, c = cc*64 + w*16 + ln
        float* pb = part + ((size_t)(b * NCH1 + sb) * HQ) * Cc + cc * 64 + w * 16 + ln;
#pragma unroll
        for (int reg = 0; reg < 4; ++reg) {
            pb[(size_t)(lg * 4 + reg) * Cc]      = acc0[reg];
            pb[(size_t)(16 + lg * 4 + reg) * Cc] = acc1[reg];
        }
        __syncthreads();
        if (cc < 3) {
#pragma unroll
            for (int k = 0; k < 16; ++k) {
                int row = w + 4 * k;
                float4 v = *(const float4*)(xbase + (size_t)((cc + 1) * 64 + row) * Ss + l * 4);
                ushort4 u; u.x = f2bf(v.x); u.y = f2bf(v.y); u.z = f2bf(v.z); u.w = f2bf(v.w);
                *(ushort4*)&xls[row][l * 4] = u;
            }
        }
        __syncthreads();
    }
}

// ---------------- K3b: reduce partials over 128 s-blocks ----------------
__global__ __launch_bounds__(256) void k3b_red(const float* __restrict__ part,
                                               float* __restrict__ ax) {
    int r = blockIdx.x, b = blockIdx.y, c = threadIdx.x;
    const float* p = part + (size_t)b * NCH1 * (HQ * Cc) + r * Cc + c;
    float s = 0.f;
#pragma unroll 16
    for (int j = 0; j < NCH1; ++j) s += p[(size_t)j * (HQ * Cc)];
    ax[((size_t)b * HQ + r) * Cc + c] = s;
}

// ---------------- K4a: attended -> multi[b][q*512+h*64+d] ----------------
__global__ __launch_bounds__(256) void k4a_att(const float* __restrict__ ax,
                                               const float* __restrict__ Wv,
                                               const float* __restrict__ bv,
                                               float* __restrict__ multi) {
    int b = blockIdx.y, fc = blockIdx.x;   // 8 x 4 grid
    int t = threadIdx.x;
    int i = fc * 256 + t;
    int qq = i >> 9, h = (i >> 6) & 7, d = i & 63;
    int hq = h * 4 + qq, row = h * 64 + d;
    const float4* wr = (const float4*)(Wv + (size_t)row * Cc);
    const float4* ar = (const float4*)(ax + ((size_t)b * HQ + hq) * Cc);
    float dot = bv[row];
#pragma unroll 8
    for (int c4 = 0; c4 < 64; ++c4) {
        float4 wv = wr[c4], av = ar[c4];
        dot += wv.x * av.x + wv.y * av.y + wv.z * av.z + wv.w * av.w;
    }
    multi[b * 2048 + i] = dot;
}

// ---------------- K4b: out_pre[b][f] = multi[b]·Wo[f] + bo[f] ----------------
__global__ __launch_bounds__(256) void k4b_out(const float* __restrict__ multi,
                                               const float* __restrict__ Wo,
                                               const float* __restrict__ bo,
                                               float* __restrict__ out_pre) {
    int fb = blockIdx.x;   // 128 blocks x 4 f each (one per wave)
    int t = threadIdx.x, w = t >> 6, l = t & 63;
    __shared__ float ml[4][2048];
#pragma unroll
    for (int k = 0; k < 8; ++k) {
        int idx = t + 256 * k;
        ((float4*)&ml[0][0])[idx] = ((const float4*)multi)[idx];
    }
    __syncthreads();
    int f = fb * 4 + w;
    const float4* wr = (const float4*)(Wo + (size_t)f * 2048);
    float a[4] = {0.f, 0.f, 0.f, 0.f};
#pragma unroll
    for (int j = 0; j < 8; ++j) {
        float4 wv = wr[j * 64 + l];
#pragma unroll
        for (int bb = 0; bb < 4; ++bb) {
            float4 mv = *(const float4*)&ml[bb][(j * 64 + l) * 4];
            a[bb] += wv.x * mv.x + wv.y * mv.y + wv.z * mv.z + wv.w * mv.w;
        }
    }
#pragma unroll
    for (int o = 1; o < 64; o <<= 1) {
#pragma unroll
        for (int bb = 0; bb < 4; ++bb) a[bb] += __shfl_xor(a[bb], o);
    }
    if (l == 0) {
        float bof = bo[f];
#pragma unroll
        for (int bb = 0; bb < 4; ++bb) out_pre[bb * Ff + f] = a[bb] + bof;
    }
}

// ---------------- K4c: LayerNorm over F=512 ----------------
__global__ __launch_bounds__(512) void k4c_ln(const float* __restrict__ out_pre,
                                              const float* __restrict__ gamma,
                                              const float* __restrict__ beta,
                                              float* __restrict__ out) {
    int b = blockIdx.x, t = threadIdx.x;
    float v = out_pre[b * Ff + t];
    float s = v;
#pragma unroll
    for (int o = 1; o < 64; o <<= 1) s += __shfl_xor(s, o);
    __shared__ float red[8], red2[8];
    int w = t >> 6;
    if ((t & 63) == 0) red[w] = s;
    __syncthreads();
    float mu = 0.f;
#pragma unroll
    for (int ww = 0; ww < 8; ++ww) mu += red[ww];
    mu *= (1.f / Ff);
    float d = v - mu;
    float s2 = d * d;
#pragma unroll
    for (int o = 1; o < 64; o <<= 1) s2 += __shfl_xor(s2, o);
    if ((t & 63) == 0) red2[w] = s2;
    __syncthreads();
    float var = 0.f;
#pragma unroll
    for (int ww = 0; ww < 8; ++ww) var += red2[ww];
    var *= (1.f / Ff);
    out[b * Ff + t] = d * rsqrtf(var + LN_EPSf) * gamma[t] + beta[t];
}

extern "C" void kernel_launch(void* const* d_in, const int* in_sizes, int n_in,
                              void* d_out, int out_size, void* d_ws, size_t ws_size,
                              hipStream_t stream) {
    const float* x       = (const float*)d_in[0];
    const float* queries = (const float*)d_in[1];
    const float* Wk      = (const float*)d_in[2];
    const float* bk      = (const float*)d_in[3];
    const float* Wv      = (const float*)d_in[4];
    const float* bv      = (const float*)d_in[5];
    const float* Wo      = (const float*)d_in[6];
    const float* bo      = (const float*)d_in[7];
    const float* gamma   = (const float*)d_in[8];
    const float* beta    = (const float*)d_in[9];
    float* out = (float*)d_out;
    float* ws  = (float*)d_ws;

    // ws layout (floats); total ~34 MB
    float*  qb      = ws;                  // 32
    float*  Mrow    = ws + 32;             // 128
    float*  iLrow   = ws + 160;            // 128
    float*  pM      = ws + 288;            // 16384
    float*  pL      = ws + 16672;          // 16384
    float*  multi   = ws + 33056;          // 8192
    float*  out_pre = ws + 41248;          // 2048
    float*  ax      = ws + 43296;          // 32768
    ushort* qWbf    = (ushort*)(ws + 76064);         // 8192 ushorts = 4096 floats
    float*  scoresT = ws + 81920;                    // 4,194,304  [b][32][S]
    float*  part    = ws + 81920 + 4194304;          // 4,194,304  [b][128][32][256]

    k0_prep    <<<32, 256, 0, stream>>>(queries, Wk, bk, qWbf, qb);
    k1_scores  <<<dim3(NCH1, 4), 256, 0, stream>>>(x, qWbf, qb, scoresT, pM, pL);
    k2b_combine<<<128, 64, 0, stream>>>(pM, pL, Mrow, iLrow);
    k3_ax      <<<dim3(NCH1, 4), 256, 0, stream>>>(x, scoresT, Mrow, iLrow, part);
    k3b_red    <<<dim3(HQ, 4), 256, 0, stream>>>(part, ax);
    k4a_att    <<<dim3(8, 4), 256, 0, stream>>>(ax, Wv, bv, multi);
    k4b_out    <<<128, 256, 0, stream>>>(multi, Wo, bo, out_pre);
    k4c_ln     <<<4, 512, 0, stream>>>(out_pre, gamma, beta, out);
}